// Round 4
// baseline (73.419 us; speedup 1.0000x reference)
//
#include <hip/hip_runtime.h>

#define N_QUBITS 4
#define N_LAYERS 6
#define NSTATES  16   // 2^N_QUBITS
#define SPT      2    // samples per thread

__device__ __forceinline__ float2 cmul(float2 a, float2 b) {
    return make_float2(a.x * b.x - a.y * b.y, a.x * b.y + a.y * b.x);
}
__device__ __forceinline__ float2 cadd(float2 a, float2 b) {
    return make_float2(a.x + b.x, a.y + b.y);
}

// ---------------------------------------------------------------------------
// Fused kernel. Phase 1: each block builds the batch-uniform 16x16 circuit
// unitary in LDS (256 threads = 16 columns x 16 states, ROLLED gate loops —
// an unrolled per-thread build spilled and ran 86 us in round 1's version).
// Phase 2: transpose to row-contiguous layout. Phase 3: per-thread apply to
// SPT samples: v = RY product state (real, rank-1), amp = U v via broadcast
// ds_read_b128 (wave-uniform addresses -> no bank conflicts), z via sign
// butterfly. One kernel = no build-launch drain, no U global round-trip.
// ---------------------------------------------------------------------------
__global__ __launch_bounds__(256) void qc_fused_kernel(
        const float* __restrict__ inputs,   // (B, 4)
        const float* __restrict__ weights,  // (6, 4, 3)
        float* __restrict__ out,            // (B, 4)
        int B) {
    __shared__ float2 rotm[N_LAYERS * N_QUBITS][4];
    __shared__ float2 st[NSTATES][NSTATES];   // [column c][state i]
    __shared__ float  Ut[NSTATES][2 * NSTATES]; // row i: re/im interleaved over k

    const int t = threadIdx.x;

    // --- Phase 0: Rot matrices (threads 0..23) ---
    if (t < N_LAYERS * N_QUBITS) {
        const float phi   = weights[t * 3 + 0];
        const float theta = weights[t * 3 + 1];
        const float omega = weights[t * 3 + 2];
        float sth, cth;
        sincosf(theta * 0.5f, &sth, &cth);
        const float a1 = -(phi + omega) * 0.5f;
        const float a2 =  (phi - omega) * 0.5f;
        float s1, c1, s2, c2;
        sincosf(a1, &s1, &c1);
        sincosf(a2, &s2, &c2);
        rotm[t][0] = make_float2( c1 * cth,  s1 * cth);   // m00
        rotm[t][1] = make_float2(-c2 * sth, -s2 * sth);   // m01
        rotm[t][2] = make_float2( c2 * sth, -s2 * sth);   // m10
        rotm[t][3] = make_float2( c1 * cth, -s1 * cth);   // m11
    }

    // --- Phase 1: simulate all 16 basis columns through the circuit ---
    const int c = t >> 4;     // column (input basis state)
    const int i = t & 15;     // state index within column
    st[c][i] = make_float2(i == c ? 1.0f : 0.0f, 0.0f);
    __syncthreads();

    #pragma unroll 1
    for (int l = 0; l < N_LAYERS; ++l) {
        #pragma unroll 1
        for (int w = 0; w < N_QUBITS; ++w) {
            const int bit = 8 >> w;
            if (!(i & bit)) {
                const int j = i | bit;
                const float2 a0 = st[c][i];
                const float2 a1v = st[c][j];
                const float2 m00 = rotm[l * N_QUBITS + w][0];
                const float2 m01 = rotm[l * N_QUBITS + w][1];
                const float2 m10 = rotm[l * N_QUBITS + w][2];
                const float2 m11 = rotm[l * N_QUBITS + w][3];
                st[c][i] = cadd(cmul(m00, a0), cmul(m01, a1v));
                st[c][j] = cadd(cmul(m10, a0), cmul(m11, a1v));
            }
            __syncthreads();
        }
        // ring of CNOTs with range r: pure basis-label permutation
        const int r = l % (N_QUBITS - 1) + 1;
        int fi = i;
        #pragma unroll
        for (int w = 0; w < N_QUBITS; ++w) {
            const int tb = 8 >> ((w + r) & 3);
            if ((fi >> (3 - w)) & 1) fi ^= tb;
        }
        const float2 a = st[c][i];
        __syncthreads();
        st[c][fi] = a;
        __syncthreads();
    }

    // --- Phase 2: transpose to row-contiguous: Ut[i][2k..] = <i|U|k> ---
    Ut[i][2 * c + 0] = st[c][i].x;
    Ut[i][2 * c + 1] = st[c][i].y;
    __syncthreads();

    // --- Phase 3: apply to SPT samples ---
    #pragma unroll
    for (int sidx = 0; sidx < SPT; ++sidx) {
        const int b = blockIdx.x * (blockDim.x * SPT) + sidx * blockDim.x + t;
        if (b >= B) continue;

        const float4 xin = reinterpret_cast<const float4*>(inputs)[b];
        float s0, c0, s1, c1, s2, c2, s3, c3;
        __sincosf(xin.x * 0.5f, &s0, &c0);
        __sincosf(xin.y * 0.5f, &s1, &c1);
        __sincosf(xin.z * 0.5f, &s2, &c2);
        __sincosf(xin.w * 0.5f, &s3, &c3);

        const float vA[4] = { c0 * c1, c0 * s1, s0 * c1, s0 * s1 };  // wires 0,1
        const float vB[4] = { c2 * c3, c2 * s3, s2 * c3, s2 * s3 };  // wires 2,3
        float v[NSTATES];
        #pragma unroll
        for (int a = 0; a < 4; ++a)
            #pragma unroll
            for (int q = 0; q < 4; ++q)
                v[a * 4 + q] = vA[a] * vB[q];

        float p[NSTATES];
        #pragma unroll
        for (int row = 0; row < NSTATES; ++row) {
            const float4* r4 = reinterpret_cast<const float4*>(&Ut[row][0]);
            float re = 0.0f, im = 0.0f;
            #pragma unroll
            for (int q = 0; q < 8; ++q) {      // 8 float4 = 16 complex entries
                const float4 u4 = r4[q];
                re = fmaf(u4.x, v[2 * q],     re);
                im = fmaf(u4.y, v[2 * q],     im);
                re = fmaf(u4.z, v[2 * q + 1], re);
                im = fmaf(u4.w, v[2 * q + 1], im);
            }
            p[row] = re * re + im * im;
        }

        // Sign butterfly: z_w = sum_i (1 - 2*bit_{3-w}(i)) * p[i]
        float sa[8], da[8];
        #pragma unroll
        for (int j = 0; j < 8; ++j) {
            sa[j] = p[2 * j] + p[2 * j + 1];
            da[j] = p[2 * j] - p[2 * j + 1];
        }
        const float z3 = ((da[0] + da[1]) + (da[2] + da[3])) +
                         ((da[4] + da[5]) + (da[6] + da[7]));
        float sb[4], db[4];
        #pragma unroll
        for (int j = 0; j < 4; ++j) {
            sb[j] = sa[2 * j] + sa[2 * j + 1];
            db[j] = sa[2 * j] - sa[2 * j + 1];
        }
        const float z2 = (db[0] + db[1]) + (db[2] + db[3]);
        const float z1 = (sb[0] - sb[1]) + (sb[2] - sb[3]);
        const float z0 = (sb[0] + sb[1]) - (sb[2] + sb[3]);

        reinterpret_cast<float4*>(out)[b] = make_float4(z0, z1, z2, z3);
    }
}

extern "C" void kernel_launch(void* const* d_in, const int* in_sizes, int n_in,
                              void* d_out, int out_size, void* d_ws, size_t ws_size,
                              hipStream_t stream) {
    const float* inputs  = (const float*)d_in[0];   // (B, 4) float32
    const float* weights = (const float*)d_in[1];   // (6, 4, 3) float32
    float* out = (float*)d_out;                     // (B, 4) float32
    const int B = in_sizes[0] / N_QUBITS;

    const int block = 256;
    const int grid = (B + block * SPT - 1) / (block * SPT);   // 512 blocks @ B=262144
    qc_fused_kernel<<<grid, block, 0, stream>>>(inputs, weights, out, B);
}

// Round 5
// 69.915 us; speedup vs baseline: 1.0501x; 1.0501x over previous
//
#include <hip/hip_runtime.h>

#define N_QUBITS 4
#define N_LAYERS 6
#define NSTATES  16   // 2^N_QUBITS

__device__ __forceinline__ float2 cmul(float2 a, float2 b) {
    return make_float2(a.x * b.x - a.y * b.y, a.x * b.y + a.y * b.x);
}
__device__ __forceinline__ float2 cadd(float2 a, float2 b) {
    return make_float2(a.x + b.x, a.y + b.y);
}

// ---------------------------------------------------------------------------
// Pre-kernel: build the batch-uniform 16x16 circuit unitary U into d_ws.
// ONE block, 256 threads = 16 columns x 16 states, state in LDS, ROLLED gate
// loops (low VGPR, tiny code — an unrolled per-thread build spilled and ran
// 86 us on one cold wave in round 1).  ~3-5 us incl. launch.
// U row-major interleaved re/im: U[2*(i*16+k)+{0,1}] = <i|U|k>.
//
// NOTE round-4 post-mortem: fusing this into the apply kernel REGRESSED
// (69->73 us): every block paid the 36-barrier build and U reads moved from
// the scalar-cache path to the LDS return bus. Keep the two-kernel split.
// ---------------------------------------------------------------------------
__global__ __launch_bounds__(256) void build_u_kernel(
        const float* __restrict__ weights, float* __restrict__ U) {
    __shared__ float2 rotm[N_LAYERS * N_QUBITS][4];
    __shared__ float2 st[NSTATES][NSTATES];   // [column c][state i]

    const int t = threadIdx.x;
    if (t < N_LAYERS * N_QUBITS) {
        const float phi   = weights[t * 3 + 0];
        const float theta = weights[t * 3 + 1];
        const float omega = weights[t * 3 + 2];
        float sth, cth;
        sincosf(theta * 0.5f, &sth, &cth);
        const float a1 = -(phi + omega) * 0.5f;
        const float a2 =  (phi - omega) * 0.5f;
        float s1, c1, s2, c2;
        sincosf(a1, &s1, &c1);
        sincosf(a2, &s2, &c2);
        rotm[t][0] = make_float2( c1 * cth,  s1 * cth);   // m00
        rotm[t][1] = make_float2(-c2 * sth, -s2 * sth);   // m01
        rotm[t][2] = make_float2( c2 * sth, -s2 * sth);   // m10
        rotm[t][3] = make_float2( c1 * cth, -s1 * cth);   // m11
    }

    const int c = t >> 4;     // column (input basis state)
    const int i = t & 15;     // state index within column
    st[c][i] = make_float2(i == c ? 1.0f : 0.0f, 0.0f);
    __syncthreads();

    #pragma unroll 1
    for (int l = 0; l < N_LAYERS; ++l) {
        #pragma unroll 1
        for (int w = 0; w < N_QUBITS; ++w) {
            const int bit = 8 >> w;
            if (!(i & bit)) {
                const int j = i | bit;
                const float2 a0 = st[c][i];
                const float2 a1v = st[c][j];
                const float2 m00 = rotm[l * N_QUBITS + w][0];
                const float2 m01 = rotm[l * N_QUBITS + w][1];
                const float2 m10 = rotm[l * N_QUBITS + w][2];
                const float2 m11 = rotm[l * N_QUBITS + w][3];
                st[c][i] = cadd(cmul(m00, a0), cmul(m01, a1v));
                st[c][j] = cadd(cmul(m10, a0), cmul(m11, a1v));
            }
            __syncthreads();
        }
        // ring of CNOTs with range r: pure basis-label permutation
        const int r = l % (N_QUBITS - 1) + 1;
        int fi = i;
        #pragma unroll
        for (int w = 0; w < N_QUBITS; ++w) {
            const int tb = 8 >> ((w + r) & 3);
            if ((fi >> (3 - w)) & 1) fi ^= tb;
        }
        const float2 a = st[c][i];
        __syncthreads();
        st[c][fi] = a;
        __syncthreads();
    }

    // U[i][c] = st[c][i]
    U[2 * (i * NSTATES + c) + 0] = st[c][i].x;
    U[2 * (i * NSTATES + c) + 1] = st[c][i].y;
}

// ---------------------------------------------------------------------------
// Main kernel: v = RY product state (real, rank-1), amp = U @ v, z via sign
// butterfly. U address is wave-uniform -> compiler emits scalar loads
// (scalar cache broadcast, no LDS traffic). ~610 VALU/sample, ~2 us total.
// ---------------------------------------------------------------------------
__global__ __launch_bounds__(256) void qc_apply_kernel(
        const float* __restrict__ inputs,   // (B, 4)
        const float* __restrict__ U,        // 16x16 complex, interleaved
        float* __restrict__ out,            // (B, 4)
        int B) {
    const int b = blockIdx.x * blockDim.x + threadIdx.x;
    if (b >= B) return;

    const float4 xin = reinterpret_cast<const float4*>(inputs)[b];
    float s0, c0, s1, c1, s2, c2, s3, c3;
    __sincosf(xin.x * 0.5f, &s0, &c0);
    __sincosf(xin.y * 0.5f, &s1, &c1);
    __sincosf(xin.z * 0.5f, &s2, &c2);
    __sincosf(xin.w * 0.5f, &s3, &c3);

    // v[i], i bits (b3 b2 b1 b0) = wires (0,1,2,3); bit=1 -> sin
    const float vA[4] = { c0 * c1, c0 * s1, s0 * c1, s0 * s1 };  // wires 0,1
    const float vB[4] = { c2 * c3, c2 * s3, s2 * c3, s2 * s3 };  // wires 2,3
    float v[NSTATES];
    #pragma unroll
    for (int a = 0; a < 4; ++a)
        #pragma unroll
        for (int q = 0; q < 4; ++q)
            v[a * 4 + q] = vA[a] * vB[q];

    float p[NSTATES];
    #pragma unroll
    for (int i = 0; i < NSTATES; ++i) {
        const float4* row = reinterpret_cast<const float4*>(U + 2 * NSTATES * i);
        float re = 0.0f, im = 0.0f;
        #pragma unroll
        for (int q = 0; q < 8; ++q) {          // 8 float4 = 16 complex entries
            const float4 u4 = row[q];
            re = fmaf(u4.x, v[2 * q],     re);
            im = fmaf(u4.y, v[2 * q],     im);
            re = fmaf(u4.z, v[2 * q + 1], re);
            im = fmaf(u4.w, v[2 * q + 1], im);
        }
        p[i] = re * re + im * im;
    }

    // Sign butterfly: z_w = sum_i (1 - 2*bit_{3-w}(i)) * p[i]
    float sa[8], da[8];
    #pragma unroll
    for (int j = 0; j < 8; ++j) {
        sa[j] = p[2 * j] + p[2 * j + 1];
        da[j] = p[2 * j] - p[2 * j + 1];
    }
    const float z3 = ((da[0] + da[1]) + (da[2] + da[3])) +
                     ((da[4] + da[5]) + (da[6] + da[7]));
    float sb[4], db[4];
    #pragma unroll
    for (int j = 0; j < 4; ++j) {
        sb[j] = sa[2 * j] + sa[2 * j + 1];
        db[j] = sa[2 * j] - sa[2 * j + 1];
    }
    const float z2 = (db[0] + db[1]) + (db[2] + db[3]);
    const float z1 = (sb[0] - sb[1]) + (sb[2] - sb[3]);
    const float z0 = (sb[0] + sb[1]) - (sb[2] + sb[3]);

    reinterpret_cast<float4*>(out)[b] = make_float4(z0, z1, z2, z3);
}

extern "C" void kernel_launch(void* const* d_in, const int* in_sizes, int n_in,
                              void* d_out, int out_size, void* d_ws, size_t ws_size,
                              hipStream_t stream) {
    const float* inputs  = (const float*)d_in[0];   // (B, 4) float32
    const float* weights = (const float*)d_in[1];   // (6, 4, 3) float32
    float* out = (float*)d_out;                     // (B, 4) float32
    float* U   = (float*)d_ws;                      // 512 floats scratch
    const int B = in_sizes[0] / N_QUBITS;

    build_u_kernel<<<1, 256, 0, stream>>>(weights, U);

    const int block = 256;
    const int grid = (B + block - 1) / block;
    qc_apply_kernel<<<grid, block, 0, stream>>>(inputs, U, out, B);
}